// Round 22
// baseline (465.771 us; speedup 1.0000x reference)
//
#include <hip/hip_runtime.h>

// RelGCN round 22: K=64 full-line gemm2 (16B/lane A, halved VMEM instr rate)
// + 5x gemm2 repetition for exact per-kernel timing via dur_us arithmetic
// (dur = C + 5g, C ~= 211 known from r21 ledger).
//   prep     : hbf = bf16(x@W1+b1) swizzled              (r18 verbatim)
//   gemm1    : t = tanh(bf16 gemm); emits adjq row-major (r18 verbatim)
//   prep_q16 : hq = sat_i8((t@W2+b2)*64 + dither), 16-granular (r19 verified)
//   gemm2    : part[kh] = i32 K=64 gemm, barrier-free, k-split, 4-slot
//   finish   : out = tanh((part0+part1)*inv)

#define NN 8192
#define TS 516  // f32 LDS row stride (gemm1)

typedef __attribute__((ext_vector_type(4))) float float4v;
typedef __attribute__((ext_vector_type(8))) short short8v;
typedef __attribute__((ext_vector_type(4))) int int4v;

__device__ inline unsigned short f2bf(float f) {
  unsigned int u = __builtin_bit_cast(unsigned int, f);
  return (unsigned short)((u + 0x7FFFu + ((u >> 16) & 1u)) >> 16);  // RNE
}

__device__ inline float tri_dither(unsigned int e) {
  unsigned int s = e * 2654435761u;
  s ^= s >> 16;
  s *= 2246822519u;
  s ^= s >> 13;
  return ((float)((s & 0xffffu) + (s >> 16)) * (1.f / 65536.f)) - 1.f;
}

// ---------------- prep (r18 verbatim): hbf = bf16(in@W+b) swizzled ----------------
__global__ __launch_bounds__(256) void prep(
    const float* __restrict__ in, const float* __restrict__ W,
    const float* __restrict__ b, unsigned short* __restrict__ hbf) {
  __shared__ float Ws[64 * 64];
  const int tid = threadIdx.x;
  const int r = blockIdx.x >> 8;
  const int g = blockIdx.x & 255;
  const int ml = tid >> 3;
  const int j0 = (tid & 7) * 8;
  const int m = g * 32 + ml;
#pragma unroll
  for (int i = 0; i < 16; ++i) Ws[tid + i * 256] = W[r * 4096 + tid + i * 256];
  float4v xr[16];
#pragma unroll
  for (int i = 0; i < 16; ++i) xr[i] = *(const float4v*)&in[(size_t)m * 64 + i * 4];
  float acc[8];
  {
    const float4v b0 = *(const float4v*)&b[r * 64 + j0];
    const float4v b1 = *(const float4v*)&b[r * 64 + j0 + 4];
#pragma unroll
    for (int jj = 0; jj < 4; ++jj) { acc[jj] = b0[jj]; acc[jj + 4] = b1[jj]; }
  }
  __syncthreads();
#pragma unroll
  for (int fi = 0; fi < 16; ++fi) {
    const float4v xv = xr[fi];
#pragma unroll
    for (int df = 0; df < 4; ++df) {
      const int f = fi * 4 + df;
      const float a = xv[df];
      const float4v w0 = *(const float4v*)&Ws[f * 64 + j0];
      const float4v w1 = *(const float4v*)&Ws[f * 64 + j0 + 4];
#pragma unroll
      for (int jj = 0; jj < 4; ++jj) {
        acc[jj] += a * w0[jj];
        acc[jj + 4] += a * w1[jj];
      }
    }
  }
  const size_t base = ((size_t)(r * 1024 + (m >> 3)) * 64) * 8 + (m & 7);
#pragma unroll
  for (int jj = 0; jj < 8; ++jj)
    hbf[base + (size_t)(j0 + jj) * 8] = f2bf(acc[jj]);
}

// ---- prep_q16 (r19 verified): hq = sat_i8((in@W+b)*S + dither), 16-granular ----
__global__ __launch_bounds__(256) void prep_q16(
    const float* __restrict__ in, const float* __restrict__ W,
    const float* __restrict__ b, unsigned char* __restrict__ hq, float S) {
  __shared__ float Ws[64 * 64];
  const int tid = threadIdx.x;
  const int r = blockIdx.x >> 8;
  const int g = blockIdx.x & 255;
  const int ml = tid >> 3;
  const int j0 = (tid & 7) * 8;
  const int m = g * 32 + ml;
#pragma unroll
  for (int i = 0; i < 16; ++i) Ws[tid + i * 256] = W[r * 4096 + tid + i * 256];
  float4v xr[16];
#pragma unroll
  for (int i = 0; i < 16; ++i) xr[i] = *(const float4v*)&in[(size_t)m * 64 + i * 4];
  float acc[8];
  {
    const float4v b0 = *(const float4v*)&b[r * 64 + j0];
    const float4v b1 = *(const float4v*)&b[r * 64 + j0 + 4];
#pragma unroll
    for (int jj = 0; jj < 4; ++jj) { acc[jj] = b0[jj]; acc[jj + 4] = b1[jj]; }
  }
  __syncthreads();
#pragma unroll
  for (int fi = 0; fi < 16; ++fi) {
    const float4v xv = xr[fi];
#pragma unroll
    for (int df = 0; df < 4; ++df) {
      const int f = fi * 4 + df;
      const float a = xv[df];
      const float4v w0 = *(const float4v*)&Ws[f * 64 + j0];
      const float4v w1 = *(const float4v*)&Ws[f * 64 + j0 + 4];
#pragma unroll
      for (int jj = 0; jj < 4; ++jj) {
        acc[jj] += a * w0[jj];
        acc[jj + 4] += a * w1[jj];
      }
    }
  }
  const size_t base = ((size_t)(r * 512 + (m >> 4)) * 64) * 16 + (m & 15);
#pragma unroll
  for (int jj = 0; jj < 8; ++jj) {
    float v = acc[jj] * S + tri_dither((unsigned)((r * NN + m) * 64 + j0 + jj));
    int q = (int)rintf(v);
    q = q > 127 ? 127 : (q < -127 ? -127 : q);
    hq[base + (size_t)(j0 + jj) * 16] = (unsigned char)(q & 0xff);
  }
}

// ---- gemm1 (r18 verbatim): staged bf16 + fused row-major i8 emission ----
__global__ __launch_bounds__(256) void gemm1_emit(
    const float* __restrict__ adj, const unsigned short* __restrict__ hbf,
    float* __restrict__ out, unsigned char* __restrict__ adjq) {
  __shared__ float lds[2 * 16 * TS];
  float* buf0 = lds;
  float* buf1 = lds + 16 * TS;
  const int tid = threadIdx.x;
  const int w = tid >> 6;
  const int l = tid & 63;
  const int lrow = l & 15;
  const int lk = l >> 4;
  const int mb = blockIdx.x;
  const int phase = (mb * 29) % 48;
  const int srow = tid >> 4;
  const int sseg = tid & 15;
  const float* arow = adj + (size_t)(mb * 16 + srow) * NN + sseg * 4;
  unsigned char* a8row = adjq + (size_t)(mb * 16 + srow) * NN + sseg * 4;

  float4v acc0 = {0.f, 0.f, 0.f, 0.f}, acc1 = acc0, acc2 = acc0, acc3 = acc0;
  float4v P0, P1, P2, P3, P4, P5, P6, P7, Q0, Q1, Q2, Q3, Q4, Q5, Q6, Q7;

#define TW(TQ) ((TQ) + phase >= 48 ? (TQ) + phase - 48 : (TQ) + phase)
#define TOFF(T) (((size_t)((T) >> 4) << 26) + ((size_t)((T) & 15) << 9))

#define GLOAD(T, S)                                                            \
  do {                                                                         \
    const float* pa_ = arow + TOFF(T);                                         \
    S##0 = __builtin_nontemporal_load((const float4v*)(pa_));                  \
    S##1 = __builtin_nontemporal_load((const float4v*)(pa_ + 64));             \
    S##2 = __builtin_nontemporal_load((const float4v*)(pa_ + 128));            \
    S##3 = __builtin_nontemporal_load((const float4v*)(pa_ + 192));            \
    S##4 = __builtin_nontemporal_load((const float4v*)(pa_ + 256));            \
    S##5 = __builtin_nontemporal_load((const float4v*)(pa_ + 320));            \
    S##6 = __builtin_nontemporal_load((const float4v*)(pa_ + 384));            \
    S##7 = __builtin_nontemporal_load((const float4v*)(pa_ + 448));            \
  } while (0)

#define Q8ST(S, K)                                                             \
  *(unsigned int*)(q8_ + (K) * 64) =                                           \
      (unsigned)(S[0] * 1040384.f + 0.5f) |                                    \
      ((unsigned)(S[1] * 1040384.f + 0.5f) << 8) |                             \
      ((unsigned)(S[2] * 1040384.f + 0.5f) << 16) |                            \
      ((unsigned)(S[3] * 1040384.f + 0.5f) << 24)

#define DSWRITE(BUF, S, T8)                                                    \
  do {                                                                         \
    float* p_ = (BUF) + srow * TS + sseg * 4;                                  \
    *(float4v*)(p_) = S##0;                                                    \
    *(float4v*)(p_ + 64) = S##1;                                               \
    *(float4v*)(p_ + 128) = S##2;                                              \
    *(float4v*)(p_ + 192) = S##3;                                              \
    *(float4v*)(p_ + 256) = S##4;                                              \
    *(float4v*)(p_ + 320) = S##5;                                              \
    *(float4v*)(p_ + 384) = S##6;                                              \
    *(float4v*)(p_ + 448) = S##7;                                              \
    unsigned char* q8_ = a8row + (T8);                                         \
    Q8ST(S##0, 0); Q8ST(S##1, 1); Q8ST(S##2, 2); Q8ST(S##3, 3);                \
    Q8ST(S##4, 4); Q8ST(S##5, 5); Q8ST(S##6, 6); Q8ST(S##7, 7);                \
  } while (0)

#define DO_CHUNK(CUR, CC, B0, B1, B2, B3)                                      \
  do {                                                                         \
    const float* ap_ = (CUR) + lrow * TS + (w * 4 + (CC)) * 32 + lk * 8;       \
    const float4v a0_ = *(const float4v*)ap_;                                  \
    const float4v a1_ = *(const float4v*)(ap_ + 4);                            \
    short8v av_;                                                               \
    av_[0] = (short)f2bf(a0_[0]); av_[1] = (short)f2bf(a0_[1]);                \
    av_[2] = (short)f2bf(a0_[2]); av_[3] = (short)f2bf(a0_[3]);                \
    av_[4] = (short)f2bf(a1_[0]); av_[5] = (short)f2bf(a1_[1]);                \
    av_[6] = (short)f2bf(a1_[2]); av_[7] = (short)f2bf(a1_[3]);                \
    acc0 = __builtin_amdgcn_mfma_f32_16x16x32_bf16(av_, B0, acc0, 0, 0, 0);    \
    acc1 = __builtin_amdgcn_mfma_f32_16x16x32_bf16(av_, B1, acc1, 0, 0, 0);    \
    acc2 = __builtin_amdgcn_mfma_f32_16x16x32_bf16(av_, B2, acc2, 0, 0, 0);    \
    acc3 = __builtin_amdgcn_mfma_f32_16x16x32_bf16(av_, B3, acc3, 0, 0, 0);    \
  } while (0)

#define TILE(TQ, CBUF, WBUF, WS, LS)                                           \
  do {                                                                         \
    const int T_ = TW(TQ);                                                     \
    const unsigned short* pbb_ =                                               \
        hbf +                                                                  \
        ((size_t)((T_ >> 4) * 1024 + (T_ & 15) * 64 + w * 16 + lk) * 512) +    \
        lrow * 8;                                                              \
    const short8v B00 = *(const short8v*)(pbb_);                               \
    const short8v B01 = *(const short8v*)(pbb_ + 128);                         \
    const short8v B02 = *(const short8v*)(pbb_ + 256);                         \
    const short8v B03 = *(const short8v*)(pbb_ + 384);                         \
    const short8v B10 = *(const short8v*)(pbb_ + 2048);                        \
    const short8v B11 = *(const short8v*)(pbb_ + 2176);                        \
    const short8v B12 = *(const short8v*)(pbb_ + 2304);                        \
    const short8v B13 = *(const short8v*)(pbb_ + 2432);                        \
    const short8v B20 = *(const short8v*)(pbb_ + 4096);                        \
    const short8v B21 = *(const short8v*)(pbb_ + 4224);                        \
    const short8v B22 = *(const short8v*)(pbb_ + 4352);                        \
    const short8v B23 = *(const short8v*)(pbb_ + 4480);                        \
    const short8v B30 = *(const short8v*)(pbb_ + 6144);                        \
    const short8v B31 = *(const short8v*)(pbb_ + 6272);                        \
    const short8v B32 = *(const short8v*)(pbb_ + 6400);                        \
    const short8v B33 = *(const short8v*)(pbb_ + 6528);                        \
    if ((TQ) + 1 < 48) DSWRITE(WBUF, WS, TOFF(TW((TQ) + 1)));                  \
    if ((TQ) + 2 < 48) GLOAD(TW((TQ) + 2), LS);                                \
    DO_CHUNK(CBUF, 0, B00, B01, B02, B03);                                     \
    DO_CHUNK(CBUF, 1, B10, B11, B12, B13);                                     \
    DO_CHUNK(CBUF, 2, B20, B21, B22, B23);                                     \
    DO_CHUNK(CBUF, 3, B30, B31, B32, B33);                                     \
    __syncthreads();                                                           \
  } while (0)

  GLOAD(TW(0), P);
  DSWRITE(buf0, P, TOFF(TW(0)));
  GLOAD(TW(1), Q);
  __syncthreads();

#pragma unroll 1
  for (int tq = 0; tq < 48; tq += 2) {
    TILE(tq, buf0, buf1, Q, P);
    TILE(tq + 1, buf1, buf0, P, Q);
  }
#undef TILE
#undef DO_CHUNK
#undef DSWRITE
#undef Q8ST
#undef GLOAD
#undef TW

  float* red = lds;
#pragma unroll
  for (int q = 0; q < 4; ++q) {
    red[w * 1024 + (lk * 4 + q) * 64 + 0 + lrow] = acc0[q];
    red[w * 1024 + (lk * 4 + q) * 64 + 16 + lrow] = acc1[q];
    red[w * 1024 + (lk * 4 + q) * 64 + 32 + lrow] = acc2[q];
    red[w * 1024 + (lk * 4 + q) * 64 + 48 + lrow] = acc3[q];
  }
  __syncthreads();
#pragma unroll
  for (int idx = tid; idx < 1024; idx += 256) {
    const float s = red[idx] + red[1024 + idx] + red[2048 + idx] + red[3072 + idx];
    out[(size_t)mb * 1024 + idx] = tanhf(s);
  }
}

// ---- gemm2: barrier-free 8-wave, K=64 full-line A (16B/lane), k-split, 4-slot ----
__global__ __launch_bounds__(512) void gemm2_i8(
    const unsigned char* __restrict__ adjq, const unsigned char* __restrict__ hq,
    int* __restrict__ part) {
  __shared__ int red[8 * 1024];
  const int tid = threadIdx.x;
  const int w = tid >> 6;
  const int l = tid & 63;
  const int lrow = l & 15;
  const int lk = l >> 4;
  const int mb = blockIdx.x >> 1;
  const int kh = blockIdx.x & 1;
  const int poff = (mb * 13) % 24;
  const unsigned char* parow = adjq + (size_t)(mb * 16 + lrow) * NN + lk * 16;

  int4v acc0 = {0, 0, 0, 0}, acc1 = acc0, acc2 = acc0, acc3 = acc0;
  int4v pA, pB0, pB1, pB2, pB3, qA, qB0, qB1, qB2, qB3;
  int4v sA, sB0, sB1, sB2, sB3, uA, uB0, uB1, uB2, uB3;

#define TW24(IT) ((IT) + poff >= 24 ? (IT) + poff - 24 : (IT) + poff)

// 384 chunks of 64-k total; this block's half: c = TW24(it)*8 + w + kh*192.
#define ISSUE(IT, A, B0, B1, B2, B3)                                           \
  do {                                                                         \
    const int c_ = TW24(IT) * 8 + w + kh * 192;                                \
    const int r_ = c_ >> 7;                                                    \
    const int mm_ = (c_ & 127) << 6;                                           \
    A = *(const int4v*)(parow + ((size_t)r_ << 26) + mm_);                     \
    const unsigned char* pb_ =                                                 \
        hq + ((size_t)(r_ * 512 + (mm_ >> 4) + lk) * 64 + lrow) * 16;          \
    B0 = *(const int4v*)(pb_);                                                 \
    B1 = *(const int4v*)(pb_ + 256);                                           \
    B2 = *(const int4v*)(pb_ + 512);                                           \
    B3 = *(const int4v*)(pb_ + 768);                                           \
  } while (0)

#define COMPUTE(A, B0, B1, B2, B3)                                             \
  do {                                                                         \
    acc0 = __builtin_amdgcn_mfma_i32_16x16x64_i8(A, B0, acc0, 0, 0, 0);        \
    acc1 = __builtin_amdgcn_mfma_i32_16x16x64_i8(A, B1, acc1, 0, 0, 0);        \
    acc2 = __builtin_amdgcn_mfma_i32_16x16x64_i8(A, B2, acc2, 0, 0, 0);        \
    acc3 = __builtin_amdgcn_mfma_i32_16x16x64_i8(A, B3, acc3, 0, 0, 0);        \
  } while (0)

  ISSUE(0, pA, pB0, pB1, pB2, pB3);
  ISSUE(1, qA, qB0, qB1, qB2, qB3);
  ISSUE(2, sA, sB0, sB1, sB2, sB3);
#pragma unroll 1
  for (int it = 0; it < 24; it += 4) {
    ISSUE(it + 3, uA, uB0, uB1, uB2, uB3);
    COMPUTE(pA, pB0, pB1, pB2, pB3);
    if (it + 4 < 24) ISSUE(it + 4, pA, pB0, pB1, pB2, pB3);
    COMPUTE(qA, qB0, qB1, qB2, qB3);
    if (it + 5 < 24) ISSUE(it + 5, qA, qB0, qB1, qB2, qB3);
    COMPUTE(sA, sB0, sB1, sB2, sB3);
    if (it + 6 < 24) ISSUE(it + 6, sA, sB0, sB1, sB2, sB3);
    COMPUTE(uA, uB0, uB1, uB2, uB3);
  }
#undef ISSUE
#undef COMPUTE
#undef TW24

#pragma unroll
  for (int q = 0; q < 4; ++q) {
    red[w * 1024 + (lk * 4 + q) * 64 + 0 + lrow] = acc0[q];
    red[w * 1024 + (lk * 4 + q) * 64 + 16 + lrow] = acc1[q];
    red[w * 1024 + (lk * 4 + q) * 64 + 32 + lrow] = acc2[q];
    red[w * 1024 + (lk * 4 + q) * 64 + 48 + lrow] = acc3[q];
  }
  __syncthreads();
#pragma unroll
  for (int idx = tid; idx < 1024; idx += 512) {
    int s = 0;
#pragma unroll
    for (int wb = 0; wb < 8; ++wb) s += red[wb * 1024 + idx];
    part[(size_t)kh * (8192 * 64) + (size_t)mb * 1024 + idx] = s;
  }
}

__global__ __launch_bounds__(256) void finish_tanh_i32(
    const int* __restrict__ part, float* __restrict__ dst, float inv) {
  const int i = blockIdx.x * 256 + threadIdx.x;
  const int s = part[i] + part[i + 8192 * 64];
  dst[i] = tanhf((float)s * inv);
}

__global__ __launch_bounds__(256) void fill_sentinel(float* __restrict__ dst) {
  dst[blockIdx.x * 256 + threadIdx.x] = 7.0f;
}

extern "C" void kernel_launch(void* const* d_in, const int* in_sizes, int n_in,
                              void* d_out, int out_size, void* d_ws, size_t ws_size,
                              hipStream_t stream) {
  const float* x   = (const float*)d_in[0];
  const float* adj = (const float*)d_in[1];
  const float* W1  = (const float*)d_in[2];
  const float* b1  = (const float*)d_in[3];
  const float* W2  = (const float*)d_in[4];
  const float* b2  = (const float*)d_in[5];
  float* out = (float*)d_out;

  const size_t A8_B  = (size_t)3 * 8192 * 8192;   // 192 MiB
  const size_t HBF_B = (size_t)3 * 8192 * 64 * 2; // 3 MB
  const size_t T_B   = (size_t)8192 * 64 * 4;     // 2 MB
  const size_t HQ_B  = (size_t)3 * 8192 * 64;     // 1.5 MB
  const size_t P_B   = (size_t)2 * 8192 * 64 * 4; // 4 MB
  if (ws_size < A8_B + HBF_B + T_B + HQ_B + 2 * P_B) {
    fill_sentinel<<<2048, 256, 0, stream>>>(out);
    return;
  }
  unsigned char* adjq = (unsigned char*)d_ws;
  unsigned short* hbf = (unsigned short*)((char*)d_ws + A8_B);
  float* t            = (float*)((char*)d_ws + A8_B + HBF_B);
  unsigned char* hq   = (unsigned char*)((char*)d_ws + A8_B + HBF_B + T_B);
  int* part           = (int*)((char*)d_ws + A8_B + HBF_B + T_B + HQ_B);
  int* part_scr       = (int*)((char*)d_ws + A8_B + HBF_B + T_B + HQ_B + P_B);

  // layer 1: bf16 staged gemm + async row-major i8 adj emission (r18)
  prep<<<3 * 256, 256, 0, stream>>>(x, W1, b1, hbf);
  gemm1_emit<<<512, 256, 0, stream>>>(adj, hbf, t, adjq);
  // layer 2: K=64 barrier-free i8 gemm; 4 timing replicas into scratch,
  // then the real one (dur_us = C + 5*g -> g readable at +-2us)
  prep_q16<<<3 * 256, 256, 0, stream>>>(t, W2, b2, hq, 64.f);
  gemm2_i8<<<1024, 512, 0, stream>>>(adjq, hq, part_scr);
  gemm2_i8<<<1024, 512, 0, stream>>>(adjq, hq, part_scr);
  gemm2_i8<<<1024, 512, 0, stream>>>(adjq, hq, part_scr);
  gemm2_i8<<<1024, 512, 0, stream>>>(adjq, hq, part_scr);
  gemm2_i8<<<1024, 512, 0, stream>>>(adjq, hq, part);
  finish_tanh_i32<<<2048, 256, 0, stream>>>(part, out, 1.f / (1040384.f * 64.f));
}

// Round 23
// 284.208 us; speedup vs baseline: 1.6388x; 1.6388x over previous
//
#include <hip/hip_runtime.h>

// RelGCN round 23: final clean build (r22 minus timing replicas).
//   prep     : hbf = bf16(x@W1+b1) swizzled              (r18 verbatim)
//   gemm1    : t = tanh(bf16 gemm); emits adjq row-major (r18 verbatim, 190us)
//   prep_q16 : hq = sat_i8((t@W2+b2)*64 + dither), 16-granular (r19 verified)
//   gemm2    : part[kh] = i32 K=64 full-line gemm, barrier-free (51us, r22-measured)
//   finish   : out = tanh((part0+part1)*inv)

#define NN 8192
#define TS 516  // f32 LDS row stride (gemm1)

typedef __attribute__((ext_vector_type(4))) float float4v;
typedef __attribute__((ext_vector_type(8))) short short8v;
typedef __attribute__((ext_vector_type(4))) int int4v;

__device__ inline unsigned short f2bf(float f) {
  unsigned int u = __builtin_bit_cast(unsigned int, f);
  return (unsigned short)((u + 0x7FFFu + ((u >> 16) & 1u)) >> 16);  // RNE
}

__device__ inline float tri_dither(unsigned int e) {
  unsigned int s = e * 2654435761u;
  s ^= s >> 16;
  s *= 2246822519u;
  s ^= s >> 13;
  return ((float)((s & 0xffffu) + (s >> 16)) * (1.f / 65536.f)) - 1.f;
}

// ---------------- prep: hbf = bf16(in@W+b) swizzled ----------------
__global__ __launch_bounds__(256) void prep(
    const float* __restrict__ in, const float* __restrict__ W,
    const float* __restrict__ b, unsigned short* __restrict__ hbf) {
  __shared__ float Ws[64 * 64];
  const int tid = threadIdx.x;
  const int r = blockIdx.x >> 8;
  const int g = blockIdx.x & 255;
  const int ml = tid >> 3;
  const int j0 = (tid & 7) * 8;
  const int m = g * 32 + ml;
#pragma unroll
  for (int i = 0; i < 16; ++i) Ws[tid + i * 256] = W[r * 4096 + tid + i * 256];
  float4v xr[16];
#pragma unroll
  for (int i = 0; i < 16; ++i) xr[i] = *(const float4v*)&in[(size_t)m * 64 + i * 4];
  float acc[8];
  {
    const float4v b0 = *(const float4v*)&b[r * 64 + j0];
    const float4v b1 = *(const float4v*)&b[r * 64 + j0 + 4];
#pragma unroll
    for (int jj = 0; jj < 4; ++jj) { acc[jj] = b0[jj]; acc[jj + 4] = b1[jj]; }
  }
  __syncthreads();
#pragma unroll
  for (int fi = 0; fi < 16; ++fi) {
    const float4v xv = xr[fi];
#pragma unroll
    for (int df = 0; df < 4; ++df) {
      const int f = fi * 4 + df;
      const float a = xv[df];
      const float4v w0 = *(const float4v*)&Ws[f * 64 + j0];
      const float4v w1 = *(const float4v*)&Ws[f * 64 + j0 + 4];
#pragma unroll
      for (int jj = 0; jj < 4; ++jj) {
        acc[jj] += a * w0[jj];
        acc[jj + 4] += a * w1[jj];
      }
    }
  }
  const size_t base = ((size_t)(r * 1024 + (m >> 3)) * 64) * 8 + (m & 7);
#pragma unroll
  for (int jj = 0; jj < 8; ++jj)
    hbf[base + (size_t)(j0 + jj) * 8] = f2bf(acc[jj]);
}

// ---- prep_q16: hq = sat_i8((in@W+b)*S + dither), 16-granular swizzle ----
__global__ __launch_bounds__(256) void prep_q16(
    const float* __restrict__ in, const float* __restrict__ W,
    const float* __restrict__ b, unsigned char* __restrict__ hq, float S) {
  __shared__ float Ws[64 * 64];
  const int tid = threadIdx.x;
  const int r = blockIdx.x >> 8;
  const int g = blockIdx.x & 255;
  const int ml = tid >> 3;
  const int j0 = (tid & 7) * 8;
  const int m = g * 32 + ml;
#pragma unroll
  for (int i = 0; i < 16; ++i) Ws[tid + i * 256] = W[r * 4096 + tid + i * 256];
  float4v xr[16];
#pragma unroll
  for (int i = 0; i < 16; ++i) xr[i] = *(const float4v*)&in[(size_t)m * 64 + i * 4];
  float acc[8];
  {
    const float4v b0 = *(const float4v*)&b[r * 64 + j0];
    const float4v b1 = *(const float4v*)&b[r * 64 + j0 + 4];
#pragma unroll
    for (int jj = 0; jj < 4; ++jj) { acc[jj] = b0[jj]; acc[jj + 4] = b1[jj]; }
  }
  __syncthreads();
#pragma unroll
  for (int fi = 0; fi < 16; ++fi) {
    const float4v xv = xr[fi];
#pragma unroll
    for (int df = 0; df < 4; ++df) {
      const int f = fi * 4 + df;
      const float a = xv[df];
      const float4v w0 = *(const float4v*)&Ws[f * 64 + j0];
      const float4v w1 = *(const float4v*)&Ws[f * 64 + j0 + 4];
#pragma unroll
      for (int jj = 0; jj < 4; ++jj) {
        acc[jj] += a * w0[jj];
        acc[jj + 4] += a * w1[jj];
      }
    }
  }
  const size_t base = ((size_t)(r * 512 + (m >> 4)) * 64) * 16 + (m & 15);
#pragma unroll
  for (int jj = 0; jj < 8; ++jj) {
    float v = acc[jj] * S + tri_dither((unsigned)((r * NN + m) * 64 + j0 + jj));
    int q = (int)rintf(v);
    q = q > 127 ? 127 : (q < -127 ? -127 : q);
    hq[base + (size_t)(j0 + jj) * 16] = (unsigned char)(q & 0xff);
  }
}

// ---- gemm1: staged bf16 + fused row-major i8 emission ----
__global__ __launch_bounds__(256) void gemm1_emit(
    const float* __restrict__ adj, const unsigned short* __restrict__ hbf,
    float* __restrict__ out, unsigned char* __restrict__ adjq) {
  __shared__ float lds[2 * 16 * TS];
  float* buf0 = lds;
  float* buf1 = lds + 16 * TS;
  const int tid = threadIdx.x;
  const int w = tid >> 6;
  const int l = tid & 63;
  const int lrow = l & 15;
  const int lk = l >> 4;
  const int mb = blockIdx.x;
  const int phase = (mb * 29) % 48;
  const int srow = tid >> 4;
  const int sseg = tid & 15;
  const float* arow = adj + (size_t)(mb * 16 + srow) * NN + sseg * 4;
  unsigned char* a8row = adjq + (size_t)(mb * 16 + srow) * NN + sseg * 4;

  float4v acc0 = {0.f, 0.f, 0.f, 0.f}, acc1 = acc0, acc2 = acc0, acc3 = acc0;
  float4v P0, P1, P2, P3, P4, P5, P6, P7, Q0, Q1, Q2, Q3, Q4, Q5, Q6, Q7;

#define TW(TQ) ((TQ) + phase >= 48 ? (TQ) + phase - 48 : (TQ) + phase)
#define TOFF(T) (((size_t)((T) >> 4) << 26) + ((size_t)((T) & 15) << 9))

#define GLOAD(T, S)                                                            \
  do {                                                                         \
    const float* pa_ = arow + TOFF(T);                                         \
    S##0 = __builtin_nontemporal_load((const float4v*)(pa_));                  \
    S##1 = __builtin_nontemporal_load((const float4v*)(pa_ + 64));             \
    S##2 = __builtin_nontemporal_load((const float4v*)(pa_ + 128));            \
    S##3 = __builtin_nontemporal_load((const float4v*)(pa_ + 192));            \
    S##4 = __builtin_nontemporal_load((const float4v*)(pa_ + 256));            \
    S##5 = __builtin_nontemporal_load((const float4v*)(pa_ + 320));            \
    S##6 = __builtin_nontemporal_load((const float4v*)(pa_ + 384));            \
    S##7 = __builtin_nontemporal_load((const float4v*)(pa_ + 448));            \
  } while (0)

#define Q8ST(S, K)                                                             \
  *(unsigned int*)(q8_ + (K) * 64) =                                           \
      (unsigned)(S[0] * 1040384.f + 0.5f) |                                    \
      ((unsigned)(S[1] * 1040384.f + 0.5f) << 8) |                             \
      ((unsigned)(S[2] * 1040384.f + 0.5f) << 16) |                            \
      ((unsigned)(S[3] * 1040384.f + 0.5f) << 24)

#define DSWRITE(BUF, S, T8)                                                    \
  do {                                                                         \
    float* p_ = (BUF) + srow * TS + sseg * 4;                                  \
    *(float4v*)(p_) = S##0;                                                    \
    *(float4v*)(p_ + 64) = S##1;                                               \
    *(float4v*)(p_ + 128) = S##2;                                              \
    *(float4v*)(p_ + 192) = S##3;                                              \
    *(float4v*)(p_ + 256) = S##4;                                              \
    *(float4v*)(p_ + 320) = S##5;                                              \
    *(float4v*)(p_ + 384) = S##6;                                              \
    *(float4v*)(p_ + 448) = S##7;                                              \
    unsigned char* q8_ = a8row + (T8);                                         \
    Q8ST(S##0, 0); Q8ST(S##1, 1); Q8ST(S##2, 2); Q8ST(S##3, 3);                \
    Q8ST(S##4, 4); Q8ST(S##5, 5); Q8ST(S##6, 6); Q8ST(S##7, 7);                \
  } while (0)

#define DO_CHUNK(CUR, CC, B0, B1, B2, B3)                                      \
  do {                                                                         \
    const float* ap_ = (CUR) + lrow * TS + (w * 4 + (CC)) * 32 + lk * 8;       \
    const float4v a0_ = *(const float4v*)ap_;                                  \
    const float4v a1_ = *(const float4v*)(ap_ + 4);                            \
    short8v av_;                                                               \
    av_[0] = (short)f2bf(a0_[0]); av_[1] = (short)f2bf(a0_[1]);                \
    av_[2] = (short)f2bf(a0_[2]); av_[3] = (short)f2bf(a0_[3]);                \
    av_[4] = (short)f2bf(a1_[0]); av_[5] = (short)f2bf(a1_[1]);                \
    av_[6] = (short)f2bf(a1_[2]); av_[7] = (short)f2bf(a1_[3]);                \
    acc0 = __builtin_amdgcn_mfma_f32_16x16x32_bf16(av_, B0, acc0, 0, 0, 0);    \
    acc1 = __builtin_amdgcn_mfma_f32_16x16x32_bf16(av_, B1, acc1, 0, 0, 0);    \
    acc2 = __builtin_amdgcn_mfma_f32_16x16x32_bf16(av_, B2, acc2, 0, 0, 0);    \
    acc3 = __builtin_amdgcn_mfma_f32_16x16x32_bf16(av_, B3, acc3, 0, 0, 0);    \
  } while (0)

#define TILE(TQ, CBUF, WBUF, WS, LS)                                           \
  do {                                                                         \
    const int T_ = TW(TQ);                                                     \
    const unsigned short* pbb_ =                                               \
        hbf +                                                                  \
        ((size_t)((T_ >> 4) * 1024 + (T_ & 15) * 64 + w * 16 + lk) * 512) +    \
        lrow * 8;                                                              \
    const short8v B00 = *(const short8v*)(pbb_);                               \
    const short8v B01 = *(const short8v*)(pbb_ + 128);                         \
    const short8v B02 = *(const short8v*)(pbb_ + 256);                         \
    const short8v B03 = *(const short8v*)(pbb_ + 384);                         \
    const short8v B10 = *(const short8v*)(pbb_ + 2048);                        \
    const short8v B11 = *(const short8v*)(pbb_ + 2176);                        \
    const short8v B12 = *(const short8v*)(pbb_ + 2304);                        \
    const short8v B13 = *(const short8v*)(pbb_ + 2432);                        \
    const short8v B20 = *(const short8v*)(pbb_ + 4096);                        \
    const short8v B21 = *(const short8v*)(pbb_ + 4224);                        \
    const short8v B22 = *(const short8v*)(pbb_ + 4352);                        \
    const short8v B23 = *(const short8v*)(pbb_ + 4480);                        \
    const short8v B30 = *(const short8v*)(pbb_ + 6144);                        \
    const short8v B31 = *(const short8v*)(pbb_ + 6272);                        \
    const short8v B32 = *(const short8v*)(pbb_ + 6400);                        \
    const short8v B33 = *(const short8v*)(pbb_ + 6528);                        \
    if ((TQ) + 1 < 48) DSWRITE(WBUF, WS, TOFF(TW((TQ) + 1)));                  \
    if ((TQ) + 2 < 48) GLOAD(TW((TQ) + 2), LS);                                \
    DO_CHUNK(CBUF, 0, B00, B01, B02, B03);                                     \
    DO_CHUNK(CBUF, 1, B10, B11, B12, B13);                                     \
    DO_CHUNK(CBUF, 2, B20, B21, B22, B23);                                     \
    DO_CHUNK(CBUF, 3, B30, B31, B32, B33);                                     \
    __syncthreads();                                                           \
  } while (0)

  GLOAD(TW(0), P);
  DSWRITE(buf0, P, TOFF(TW(0)));
  GLOAD(TW(1), Q);
  __syncthreads();

#pragma unroll 1
  for (int tq = 0; tq < 48; tq += 2) {
    TILE(tq, buf0, buf1, Q, P);
    TILE(tq + 1, buf1, buf0, P, Q);
  }
#undef TILE
#undef DO_CHUNK
#undef DSWRITE
#undef Q8ST
#undef GLOAD
#undef TW

  float* red = lds;
#pragma unroll
  for (int q = 0; q < 4; ++q) {
    red[w * 1024 + (lk * 4 + q) * 64 + 0 + lrow] = acc0[q];
    red[w * 1024 + (lk * 4 + q) * 64 + 16 + lrow] = acc1[q];
    red[w * 1024 + (lk * 4 + q) * 64 + 32 + lrow] = acc2[q];
    red[w * 1024 + (lk * 4 + q) * 64 + 48 + lrow] = acc3[q];
  }
  __syncthreads();
#pragma unroll
  for (int idx = tid; idx < 1024; idx += 256) {
    const float s = red[idx] + red[1024 + idx] + red[2048 + idx] + red[3072 + idx];
    out[(size_t)mb * 1024 + idx] = tanhf(s);
  }
}

// ---- gemm2: barrier-free 8-wave, K=64 full-line A (16B/lane), k-split, 4-slot ----
__global__ __launch_bounds__(512) void gemm2_i8(
    const unsigned char* __restrict__ adjq, const unsigned char* __restrict__ hq,
    int* __restrict__ part) {
  __shared__ int red[8 * 1024];
  const int tid = threadIdx.x;
  const int w = tid >> 6;
  const int l = tid & 63;
  const int lrow = l & 15;
  const int lk = l >> 4;
  const int mb = blockIdx.x >> 1;
  const int kh = blockIdx.x & 1;
  const int poff = (mb * 13) % 24;
  const unsigned char* parow = adjq + (size_t)(mb * 16 + lrow) * NN + lk * 16;

  int4v acc0 = {0, 0, 0, 0}, acc1 = acc0, acc2 = acc0, acc3 = acc0;
  int4v pA, pB0, pB1, pB2, pB3, qA, qB0, qB1, qB2, qB3;
  int4v sA, sB0, sB1, sB2, sB3, uA, uB0, uB1, uB2, uB3;

#define TW24(IT) ((IT) + poff >= 24 ? (IT) + poff - 24 : (IT) + poff)

#define ISSUE(IT, A, B0, B1, B2, B3)                                           \
  do {                                                                         \
    const int c_ = TW24(IT) * 8 + w + kh * 192;                                \
    const int r_ = c_ >> 7;                                                    \
    const int mm_ = (c_ & 127) << 6;                                           \
    A = *(const int4v*)(parow + ((size_t)r_ << 26) + mm_);                     \
    const unsigned char* pb_ =                                                 \
        hq + ((size_t)(r_ * 512 + (mm_ >> 4) + lk) * 64 + lrow) * 16;          \
    B0 = *(const int4v*)(pb_);                                                 \
    B1 = *(const int4v*)(pb_ + 256);                                           \
    B2 = *(const int4v*)(pb_ + 512);                                           \
    B3 = *(const int4v*)(pb_ + 768);                                           \
  } while (0)

#define COMPUTE(A, B0, B1, B2, B3)                                             \
  do {                                                                         \
    acc0 = __builtin_amdgcn_mfma_i32_16x16x64_i8(A, B0, acc0, 0, 0, 0);        \
    acc1 = __builtin_amdgcn_mfma_i32_16x16x64_i8(A, B1, acc1, 0, 0, 0);        \
    acc2 = __builtin_amdgcn_mfma_i32_16x16x64_i8(A, B2, acc2, 0, 0, 0);        \
    acc3 = __builtin_amdgcn_mfma_i32_16x16x64_i8(A, B3, acc3, 0, 0, 0);        \
  } while (0)

  ISSUE(0, pA, pB0, pB1, pB2, pB3);
  ISSUE(1, qA, qB0, qB1, qB2, qB3);
  ISSUE(2, sA, sB0, sB1, sB2, sB3);
#pragma unroll 1
  for (int it = 0; it < 24; it += 4) {
    ISSUE(it + 3, uA, uB0, uB1, uB2, uB3);
    COMPUTE(pA, pB0, pB1, pB2, pB3);
    if (it + 4 < 24) ISSUE(it + 4, pA, pB0, pB1, pB2, pB3);
    COMPUTE(qA, qB0, qB1, qB2, qB3);
    if (it + 5 < 24) ISSUE(it + 5, qA, qB0, qB1, qB2, qB3);
    COMPUTE(sA, sB0, sB1, sB2, sB3);
    if (it + 6 < 24) ISSUE(it + 6, sA, sB0, sB1, sB2, sB3);
    COMPUTE(uA, uB0, uB1, uB2, uB3);
  }
#undef ISSUE
#undef COMPUTE
#undef TW24

#pragma unroll
  for (int q = 0; q < 4; ++q) {
    red[w * 1024 + (lk * 4 + q) * 64 + 0 + lrow] = acc0[q];
    red[w * 1024 + (lk * 4 + q) * 64 + 16 + lrow] = acc1[q];
    red[w * 1024 + (lk * 4 + q) * 64 + 32 + lrow] = acc2[q];
    red[w * 1024 + (lk * 4 + q) * 64 + 48 + lrow] = acc3[q];
  }
  __syncthreads();
#pragma unroll
  for (int idx = tid; idx < 1024; idx += 512) {
    int s = 0;
#pragma unroll
    for (int wb = 0; wb < 8; ++wb) s += red[wb * 1024 + idx];
    part[(size_t)kh * (8192 * 64) + (size_t)mb * 1024 + idx] = s;
  }
}

__global__ __launch_bounds__(256) void finish_tanh_i32(
    const int* __restrict__ part, float* __restrict__ dst, float inv) {
  const int i = blockIdx.x * 256 + threadIdx.x;
  const int s = part[i] + part[i + 8192 * 64];
  dst[i] = tanhf((float)s * inv);
}

__global__ __launch_bounds__(256) void fill_sentinel(float* __restrict__ dst) {
  dst[blockIdx.x * 256 + threadIdx.x] = 7.0f;
}

extern "C" void kernel_launch(void* const* d_in, const int* in_sizes, int n_in,
                              void* d_out, int out_size, void* d_ws, size_t ws_size,
                              hipStream_t stream) {
  const float* x   = (const float*)d_in[0];
  const float* adj = (const float*)d_in[1];
  const float* W1  = (const float*)d_in[2];
  const float* b1  = (const float*)d_in[3];
  const float* W2  = (const float*)d_in[4];
  const float* b2  = (const float*)d_in[5];
  float* out = (float*)d_out;

  const size_t A8_B  = (size_t)3 * 8192 * 8192;   // 192 MiB
  const size_t HBF_B = (size_t)3 * 8192 * 64 * 2; // 3 MB
  const size_t T_B   = (size_t)8192 * 64 * 4;     // 2 MB
  const size_t HQ_B  = (size_t)3 * 8192 * 64;     // 1.5 MB
  const size_t P_B   = (size_t)2 * 8192 * 64 * 4; // 4 MB
  if (ws_size < A8_B + HBF_B + T_B + HQ_B + P_B) {
    fill_sentinel<<<2048, 256, 0, stream>>>(out);
    return;
  }
  unsigned char* adjq = (unsigned char*)d_ws;
  unsigned short* hbf = (unsigned short*)((char*)d_ws + A8_B);
  float* t            = (float*)((char*)d_ws + A8_B + HBF_B);
  unsigned char* hq   = (unsigned char*)((char*)d_ws + A8_B + HBF_B + T_B);
  int* part           = (int*)((char*)d_ws + A8_B + HBF_B + T_B + HQ_B);

  // layer 1: bf16 staged gemm + async row-major i8 adj emission
  prep<<<3 * 256, 256, 0, stream>>>(x, W1, b1, hbf);
  gemm1_emit<<<512, 256, 0, stream>>>(adj, hbf, t, adjq);
  // layer 2: K=64 full-line barrier-free i8 gemm + finish
  prep_q16<<<3 * 256, 256, 0, stream>>>(t, W2, b2, hq, 64.f);
  gemm2_i8<<<1024, 512, 0, stream>>>(adjq, hq, part);
  finish_tanh_i32<<<2048, 256, 0, stream>>>(part, out, 1.f / (1040384.f * 64.f));
}